// Round 3
// baseline (296.630 us; speedup 1.0000x reference)
//
#include <hip/hip_runtime.h>
#include <math.h>

#define TTOT 512
#define CCH 8
#define FFR 257
#define AAH 320
#define NBF 2056      // B*F
#define BF2 2112      // padded to 33*64
#define NTIL 16       // t tiles in k_psd grid (t-tile = 32)
#define TTILE 32
#define EPSF 1e-15f
#define WSB (FFR * 8) // ws complex elements per b

// ---------------- workspace layout (floats), total ~45.3 MB ----------------
#define OFF_MBS 0                                   // [NBF][512]
#define OFF_MBN (OFF_MBS + NBF * 512)               // [NBF][512]
#define OFF_PART (OFF_MBN + NBF * 512)              // [NTIL][256][BF2]
#define OFF_PSDS (OFF_PART + NTIL * 256 * BF2)      // [NBF][8][8][2]
#define OFF_PSDN (OFF_PSDS + NBF * 128)
#define OFF_E (OFF_PSDN + NBF * 128)                // [64]
#define OFF_WS (OFF_E + 64)                         // [NBF][8][2]

// K_mask: block per bf. m = mean_c(mask); m /= (sum_t m + EPS).
// Output layout [bf][t] -> coalesced float2 stores.
__global__ __launch_bounds__(256) void k_mask(
    const float* __restrict__ mask_s, const float* __restrict__ mask_n,
    float* __restrict__ mbar_s, float* __restrict__ mbar_n) {
  int bf = blockIdx.x;
  int tid = threadIdx.x;
  int lane = tid & 63, wv = tid >> 6;
  const float2* ms = (const float2*)(mask_s + (size_t)bf * CCH * TTOT);
  const float2* mn = (const float2*)(mask_n + (size_t)bf * CCH * TTOT);
  float2 ss = make_float2(0.f, 0.f), sn = make_float2(0.f, 0.f);
#pragma unroll
  for (int c = 0; c < 8; ++c) {
    float2 a = ms[c * 256 + tid];
    ss.x += a.x; ss.y += a.y;
    float2 b = mn[c * 256 + tid];
    sn.x += b.x; sn.y += b.y;
  }
  float tots = ss.x + ss.y, totn = sn.x + sn.y;
#pragma unroll
  for (int off = 32; off > 0; off >>= 1) {
    tots += __shfl_down(tots, off);
    totn += __shfl_down(totn, off);
  }
  __shared__ float reds[4], redn[4];
  if (lane == 0) { reds[wv] = tots; redn[wv] = totn; }
  __syncthreads();
  float totS = reds[0] + reds[1] + reds[2] + reds[3];
  float totN = redn[0] + redn[1] + redn[2] + redn[3];
  float invs = 0.125f / (totS * 0.125f + EPSF);
  float invn = 0.125f / (totN * 0.125f + EPSF);
  ((float2*)(mbar_s + (size_t)bf * TTOT))[tid] = make_float2(ss.x * invs, ss.y * invs);
  ((float2*)(mbar_n + (size_t)bf * TTOT))[tid] = make_float2(sn.x * invn, sn.y * invn);
}

// K_psd: lane=bf (coalesced over f), wave=quadrant (qi,qj) of the 8x8 matrix.
// Each wave owns 16 pairs x 4 comps = 64 fp32 accumulators over the whole t-tile.
// No LDS, no barriers, no cross-wave reduce. Full matrix (no Hermitian mirror).
__global__ __launch_bounds__(256) void k_psd(
    const float* __restrict__ dr, const float* __restrict__ di,
    const float* __restrict__ mbar_s, const float* __restrict__ mbar_n,
    float* __restrict__ partial) {
  int lane = threadIdx.x & 63, wv = threadIdx.x >> 6;
  int bfb = blockIdx.x;
  int ttile = blockIdx.y;
  int bf = bfb * 64 + lane;
  if (bf > NBF - 1) bf = NBF - 1;
  int b = bf / FFR, f = bf - b * FFR;
  size_t dbase = (size_t)b * TTOT * CCH * FFR + f;
  int qi = (wv >> 1) * 4, qj = (wv & 1) * 4;
  bool diag = (qi == qj);
  int t0 = ttile * TTILE;

  float acc[16][4];
#pragma unroll
  for (int p = 0; p < 16; ++p) {
    acc[p][0] = 0.f; acc[p][1] = 0.f; acc[p][2] = 0.f; acc[p][3] = 0.f;
  }

#pragma unroll 2
  for (int tt = 0; tt < TTILE; ++tt) {
    int t = t0 + tt;
    const float* pr = dr + dbase + (size_t)t * (CCH * FFR);
    const float* pim_ = di + dbase + (size_t)t * (CCH * FFR);
    float ir[4], ii[4], jr[4], ji[4];
#pragma unroll
    for (int k = 0; k < 4; ++k) {
      ir[k] = pr[(qi + k) * FFR];
      ii[k] = pim_[(qi + k) * FFR];
    }
    if (!diag) {
#pragma unroll
      for (int k = 0; k < 4; ++k) {
        jr[k] = pr[(qj + k) * FFR];
        ji[k] = pim_[(qj + k) * FFR];
      }
    } else {
#pragma unroll
      for (int k = 0; k < 4; ++k) { jr[k] = ir[k]; ji[k] = ii[k]; }
    }
    float m_s = mbar_s[(size_t)bf * TTOT + t];
    float m_n = mbar_n[(size_t)bf * TTOT + t];
#pragma unroll
    for (int i4 = 0; i4 < 4; ++i4)
#pragma unroll
      for (int j4 = 0; j4 < 4; ++j4) {
        int p = i4 * 4 + j4;
        float pre = ir[i4] * jr[j4] + ii[i4] * ji[j4];
        float pimv = ii[i4] * jr[j4] - ir[i4] * ji[j4];
        acc[p][0] += m_s * pre; acc[p][1] += m_s * pimv;
        acc[p][2] += m_n * pre; acc[p][3] += m_n * pimv;
      }
  }

  // coalesced partial writes: [ttile][g = wv*64 + p*4 + comp][bf]
  size_t pbase = (size_t)ttile * 256 * BF2 + (size_t)wv * 64 * BF2 + bfb * 64 + lane;
#pragma unroll
  for (int p = 0; p < 16; ++p)
#pragma unroll
    for (int comp = 0; comp < 4; ++comp)
      partial[pbase + (size_t)(p * 4 + comp) * BF2] = acc[p][comp];
}

// K_reduce: grid (33, 64); wave = one g over NTIL tiles; lane = bf.
__global__ __launch_bounds__(256) void k_reduce(
    const float* __restrict__ partial, float* __restrict__ psd_s,
    float* __restrict__ psd_n) {
  int lane = threadIdx.x & 63, wv = threadIdx.x >> 6;
  int bfb = blockIdx.x;
  int g = blockIdx.y * 4 + wv;
  int bf = bfb * 64 + lane;
  const float* src = partial + (size_t)g * BF2 + bfb * 64 + lane;
  float s = 0.f;
#pragma unroll
  for (int nt = 0; nt < NTIL; ++nt) s += src[(size_t)nt * 256 * BF2];
  if (bf < NBF) {
    int w = g >> 6, rem = g & 63, p = rem >> 2, comp = rem & 3;
    int i = (w >> 1) * 4 + (p >> 2);
    int j = (w & 1) * 4 + (p & 3);
    float* dst = (comp < 2) ? psd_s : psd_n;
    dst[(size_t)bf * 128 + (i * 8 + j) * 2 + (comp & 1)] = s;
  }
}

// K2: block per (b,c): feat -> MLP -> tanh -> gvec -> block reduce -> e[b*8+c].
__global__ __launch_bounds__(320) void k2_attn(
    const float* __restrict__ psd_s, const float* __restrict__ mlp_w,
    const float* __restrict__ mlp_b, const float* __restrict__ gvec_w,
    float* __restrict__ e_out) {
  __shared__ float feat[FFR];
  __shared__ float wred[5];
  int bx = blockIdx.x;
  int b = bx >> 3, c = bx & 7;
  int tid = threadIdx.x;
  int lane = tid & 63, wv = tid >> 6;
  if (tid < FFR) {
    const float* p = psd_s + (((size_t)(b * FFR + tid)) * 8 + c) * 16;
    float sre = 0.f, sim = 0.f;
#pragma unroll
    for (int e = 0; e < 8; ++e) {
      if (e != c) { sre += p[e * 2]; sim += p[e * 2 + 1]; }
    }
    sre *= (1.0f / 7.0f);
    sim *= (1.0f / 7.0f);
    feat[tid] = sqrtf(sre * sre + sim * sim);
  }
  __syncthreads();
  float acc = mlp_b[tid];
#pragma unroll 8
  for (int f = 0; f < FFR; ++f) acc += feat[f] * mlp_w[f * AAH + tid];
  float v = tanhf(acc) * gvec_w[tid];
#pragma unroll
  for (int off = 32; off > 0; off >>= 1) v += __shfl_down(v, off);
  if (lane == 0) wred[wv] = v;
  __syncthreads();
  if (tid == 0) e_out[bx] = wred[0] + wred[1] + wred[2] + wred[3] + wred[4];
}

// K3: one wave per (b,f); barrier-free Gauss-Jordan via shuffles; fused softmax.
__global__ __launch_bounds__(256) void k3_mvdr(
    const float* __restrict__ psd_s, const float* __restrict__ psd_n,
    const float* __restrict__ e_in, const float* __restrict__ gvec_b,
    float* __restrict__ ws) {
  int lane = threadIdx.x & 63, wv = threadIdx.x >> 6;
  int bf = blockIdx.x * 4 + wv;  // 514*4 == 2056 exact
  int b = bf / FFR;
  int r = lane >> 3, c = lane & 7;
  float2 n = ((const float2*)(psd_n + (size_t)bf * 128))[lane];
  float2 s = ((const float2*)(psd_s + (size_t)bf * 128))[lane];

#pragma unroll
  for (int k = 0; k < 8; ++k) {
    float pvre = __shfl(n.x, k * 9), pvim = __shfl(n.y, k * 9);
    float dinv = 1.f / (pvre * pvre + pvim * pvim);
    float pire = pvre * dinv, piim = -pvim * dinv;
    if (r == k) {
      float2 nn = n, ss = s;
      n.x = nn.x * pire - nn.y * piim; n.y = nn.x * piim + nn.y * pire;
      s.x = ss.x * pire - ss.y * piim; s.y = ss.x * piim + ss.y * pire;
    }
    float fre = __shfl(n.x, r * 8 + k), fim = __shfl(n.y, r * 8 + k);
    float pnre = __shfl(n.x, k * 8 + c), pnim = __shfl(n.y, k * 8 + c);
    float psre = __shfl(s.x, k * 8 + c), psim = __shfl(s.y, k * 8 + c);
    if (r != k) {
      n.x -= fre * pnre - fim * pnim; n.y -= fre * pnim + fim * pnre;
      s.x -= fre * psre - fim * psim; s.y -= fre * psim + fim * psre;
    }
  }
  float trx = (r == c) ? s.x : 0.f, tryy = (r == c) ? s.y : 0.f;
#pragma unroll
  for (int off = 1; off < 64; off <<= 1) {
    trx += __shfl_xor(trx, off);
    tryy += __shfl_xor(tryy, off);
  }
  float val = 2.f * (e_in[b * 8 + c] + gvec_b[0]);
  float mx = val;
#pragma unroll
  for (int off = 1; off < 8; off <<= 1) mx = fmaxf(mx, __shfl_xor(mx, off));
  float pe = expf(val - mx);
  float psum = pe;
#pragma unroll
  for (int off = 1; off < 8; off <<= 1) psum += __shfl_xor(psum, off);
  float uc = pe / psum;
  float wre = s.x * uc, wim = s.y * uc;
#pragma unroll
  for (int off = 1; off < 8; off <<= 1) {
    wre += __shfl_xor(wre, off);
    wim += __shfl_xor(wim, off);
  }
  float tre = trx + EPSF, tim = tryy;
  float d2 = 1.f / (tre * tre + tim * tim);
  float owre = (wre * tre + wim * tim) * d2;
  float owim = (wim * tre - wre * tim) * d2;
  if (c == 0) ((float2*)ws)[(size_t)bf * 8 + r] = make_float2(owre, owim);
}

// K4: block = (b, 4-t tile); stage ws[b] in padded LDS; coalesced f reads.
__global__ __launch_bounds__(256) void k4_beam(
    const float* __restrict__ dr, const float* __restrict__ di,
    const float* __restrict__ ws, float* __restrict__ out) {
  __shared__ float2 wsp[FFR * 9];
  int b = blockIdx.y;
  int t0 = blockIdx.x * 4;
  int tid = threadIdx.x;
  const float2* wsg = (const float2*)ws + (size_t)b * WSB;
  for (int i = tid; i < FFR * 8; i += 256) {
    int f = i >> 3, c = i & 7;
    wsp[f * 9 + c] = wsg[i];
  }
  __syncthreads();
  for (int ts = 0; ts < 4; ++ts) {
    int t = t0 + ts;
    const float* drb = dr + (size_t)(b * TTOT + t) * (CCH * FFR);
    const float* dib = di + (size_t)(b * TTOT + t) * (CCH * FFR);
    for (int f = tid; f < FFR; f += 256) {
      float are = 0.f, aim = 0.f;
#pragma unroll
      for (int c = 0; c < 8; ++c) {
        float xre = drb[c * FFR + f];
        float xim = dib[c * FFR + f];
        float2 w = wsp[f * 9 + c];
        are += w.x * xre + w.y * xim;
        aim += w.x * xim - w.y * xre;
      }
      ((float2*)out)[(size_t)(b * TTOT + t) * FFR + f] = make_float2(are, aim);
    }
  }
}

extern "C" void kernel_launch(void* const* d_in, const int* in_sizes, int n_in,
                              void* d_out, int out_size, void* d_ws, size_t ws_size,
                              hipStream_t stream) {
  const float* dr = (const float*)d_in[0];
  const float* di = (const float*)d_in[1];
  const float* mask_s = (const float*)d_in[2];
  const float* mask_n = (const float*)d_in[3];
  const float* mlp_w = (const float*)d_in[4];
  const float* mlp_b = (const float*)d_in[5];
  const float* gvec_w = (const float*)d_in[6];
  const float* gvec_b = (const float*)d_in[7];
  float* out = (float*)d_out;

  float* wsf = (float*)d_ws;
  float* mbar_s = wsf + OFF_MBS;
  float* mbar_n = wsf + OFF_MBN;
  float* part = wsf + OFF_PART;
  float* psd_s = wsf + OFF_PSDS;
  float* psd_n = wsf + OFF_PSDN;
  float* e_arr = wsf + OFF_E;
  float* wsv = wsf + OFF_WS;

  hipLaunchKernelGGL(k_mask, dim3(NBF), dim3(256), 0, stream,
                     mask_s, mask_n, mbar_s, mbar_n);
  hipLaunchKernelGGL(k_psd, dim3(33, NTIL), dim3(256), 0, stream,
                     dr, di, mbar_s, mbar_n, part);
  hipLaunchKernelGGL(k_reduce, dim3(33, 64), dim3(256), 0, stream,
                     part, psd_s, psd_n);
  hipLaunchKernelGGL(k2_attn, dim3(64), dim3(320), 0, stream,
                     psd_s, mlp_w, mlp_b, gvec_w, e_arr);
  hipLaunchKernelGGL(k3_mvdr, dim3(514), dim3(256), 0, stream,
                     psd_s, psd_n, e_arr, gvec_b, wsv);
  hipLaunchKernelGGL(k4_beam, dim3(128, 8), dim3(256), 0, stream, dr, di, wsv, out);
}

// Round 5
// 253.777 us; speedup vs baseline: 1.1689x; 1.1689x over previous
//
#include <hip/hip_runtime.h>
#include <math.h>

#define TTOT 512
#define CCH 8
#define FFR 257
#define AAH 320
#define NBF 2056      // B*F
#define BF2 2112      // padded to 33*64
#define NTIL 16       // t tiles in k_psd grid
#define TTILE 32
#define EPSF 1e-15f
#define WSB (FFR * 8) // ws complex elements per b

// ---------------- workspace layout (floats), total ~45.3 MB ----------------
#define OFF_MBS 0                                   // [NBF][512]
#define OFF_MBN (OFF_MBS + NBF * 512)               // [NBF][512]
#define OFF_PART (OFF_MBN + NBF * 512)              // [NTIL][256][BF2]
#define OFF_PSDS (OFF_PART + NTIL * 256 * BF2)      // [NBF][8][8][2]
#define OFF_PSDN (OFF_PSDS + NBF * 128)
#define OFF_E (OFF_PSDN + NBF * 128)                // [64]
#define OFF_WS (OFF_E + 64)                         // [NBF][8][2]

// K_mask: block(128 thr) per bf. m = mean_c(mask); m /= (sum_t m + EPS).
// float4 loads (c-strided, coalesced) and float4 stores to [bf][t].
__global__ __launch_bounds__(128) void k_mask(
    const float* __restrict__ mask_s, const float* __restrict__ mask_n,
    float* __restrict__ mbar_s, float* __restrict__ mbar_n) {
  int bf = blockIdx.x;
  int tid = threadIdx.x;            // 0..127 ; owns t = 4tid..4tid+3
  int lane = tid & 63, wv = tid >> 6;
  const float4* ms = (const float4*)(mask_s + (size_t)bf * CCH * TTOT);
  const float4* mn = (const float4*)(mask_n + (size_t)bf * CCH * TTOT);
  float4 ss = make_float4(0.f, 0.f, 0.f, 0.f);
  float4 sn = make_float4(0.f, 0.f, 0.f, 0.f);
#pragma unroll
  for (int c = 0; c < 8; ++c) {
    float4 a = ms[c * 128 + tid];
    ss.x += a.x; ss.y += a.y; ss.z += a.z; ss.w += a.w;
    float4 b = mn[c * 128 + tid];
    sn.x += b.x; sn.y += b.y; sn.z += b.z; sn.w += b.w;
  }
  float tots = (ss.x + ss.y) + (ss.z + ss.w);
  float totn = (sn.x + sn.y) + (sn.z + sn.w);
#pragma unroll
  for (int off = 32; off > 0; off >>= 1) {
    tots += __shfl_down(tots, off);
    totn += __shfl_down(totn, off);
  }
  __shared__ float reds[2], redn[2];
  if (lane == 0) { reds[wv] = tots; redn[wv] = totn; }
  __syncthreads();
  float invs = 0.125f / ((reds[0] + reds[1]) * 0.125f + EPSF);
  float invn = 0.125f / ((redn[0] + redn[1]) * 0.125f + EPSF);
  ((float4*)(mbar_s + (size_t)bf * TTOT))[tid] =
      make_float4(ss.x * invs, ss.y * invs, ss.z * invs, ss.w * invs);
  ((float4*)(mbar_n + (size_t)bf * TTOT))[tid] =
      make_float4(sn.x * invn, sn.y * invn, sn.z * invn, sn.w * invn);
}

// K_psd: lane=bf (coalesced over f), wave=quadrant (qi,qj). mbar tile staged in
// LDS (pad 33, conflict-free). x-loads double-buffered 2 t deep, full unroll.
__global__ __launch_bounds__(256, 3) void k_psd(
    const float* __restrict__ dr, const float* __restrict__ di,
    const float* __restrict__ mbar_s, const float* __restrict__ mbar_n,
    float* __restrict__ partial) {
  __shared__ float lms[64][33];
  __shared__ float lmn[64][33];
  int tid = threadIdx.x;
  int lane = tid & 63, wv = tid >> 6;
  int bfb = blockIdx.x, ttile = blockIdx.y;
  int t0 = ttile * TTILE;

  // ---- stage mbar tile [64 bf][32 t] for both masks ----
  {
    int bfi = tid >> 2;
    int qo = (tid & 3) * 8;
    int bfg = bfb * 64 + bfi; if (bfg > NBF - 1) bfg = NBF - 1;
    const float* ps = mbar_s + (size_t)bfg * TTOT + t0 + qo;
    const float* pn = mbar_n + (size_t)bfg * TTOT + t0 + qo;
    float4 a = *(const float4*)ps;
    float4 b = *(const float4*)(ps + 4);
    float4 c = *(const float4*)pn;
    float4 d = *(const float4*)(pn + 4);
    lms[bfi][qo + 0] = a.x; lms[bfi][qo + 1] = a.y;
    lms[bfi][qo + 2] = a.z; lms[bfi][qo + 3] = a.w;
    lms[bfi][qo + 4] = b.x; lms[bfi][qo + 5] = b.y;
    lms[bfi][qo + 6] = b.z; lms[bfi][qo + 7] = b.w;
    lmn[bfi][qo + 0] = c.x; lmn[bfi][qo + 1] = c.y;
    lmn[bfi][qo + 2] = c.z; lmn[bfi][qo + 3] = c.w;
    lmn[bfi][qo + 4] = d.x; lmn[bfi][qo + 5] = d.y;
    lmn[bfi][qo + 6] = d.z; lmn[bfi][qo + 7] = d.w;
  }

  int bf = bfb * 64 + lane; if (bf > NBF - 1) bf = NBF - 1;
  int b = bf / FFR, f = bf - b * FFR;
  const float* br = dr + (size_t)b * TTOT * CCH * FFR + (size_t)t0 * CCH * FFR + f;
  const float* bi = di + (size_t)b * TTOT * CCH * FFR + (size_t)t0 * CCH * FFR + f;
  int qi = (wv >> 1) * 4, qj = (wv & 1) * 4;
  int ro[8];
#pragma unroll
  for (int k = 0; k < 4; ++k) { ro[k] = (qi + k) * FFR; ro[4 + k] = (qj + k) * FFR; }

  float acc[64];
#pragma unroll
  for (int g = 0; g < 64; ++g) acc[g] = 0.f;

  float A[16], B[16];  // [0..7] re rows (qi0-3,qj0-3), [8..15] im rows

  auto LOADX = [&](float (&buf)[16], int tt) {
    const float* pr = br + (size_t)tt * (CCH * FFR);
    const float* pi_ = bi + (size_t)tt * (CCH * FFR);
#pragma unroll
    for (int k = 0; k < 8; ++k) {
      buf[k] = pr[ro[k]];
      buf[8 + k] = pi_[ro[k]];
    }
  };
  auto FMAX = [&](float (&buf)[16], int tt) {
    float m_s = lms[lane][tt];
    float m_n = lmn[lane][tt];
#pragma unroll
    for (int i4 = 0; i4 < 4; ++i4)
#pragma unroll
      for (int j4 = 0; j4 < 4; ++j4) {
        int p = i4 * 4 + j4;
        float pre = buf[i4] * buf[4 + j4] + buf[8 + i4] * buf[12 + j4];
        float pim = buf[8 + i4] * buf[4 + j4] - buf[i4] * buf[12 + j4];
        acc[p * 4 + 0] += m_s * pre;
        acc[p * 4 + 1] += m_s * pim;
        acc[p * 4 + 2] += m_n * pre;
        acc[p * 4 + 3] += m_n * pim;
      }
  };

  LOADX(A, 0);
  LOADX(B, 1);
  __syncthreads();
#pragma unroll
  for (int tt = 0; tt < TTILE; tt += 2) {
    FMAX(A, tt);
    if (tt + 2 < TTILE) LOADX(A, tt + 2);
    FMAX(B, tt + 1);
    if (tt + 3 < TTILE) LOADX(B, tt + 3);
  }

  // coalesced partial writes: [ttile][g = wv*64 + p*4 + comp][bf]
  size_t pbase = ((size_t)ttile * 256 + wv * 64) * BF2 + bfb * 64 + lane;
#pragma unroll
  for (int g = 0; g < 64; ++g)
    partial[pbase + (size_t)g * BF2] = acc[g];
}

// K_reduce: grid (33, 64); wave = one g over NTIL tiles; lane = bf.
__global__ __launch_bounds__(256) void k_reduce(
    const float* __restrict__ partial, float* __restrict__ psd_s,
    float* __restrict__ psd_n) {
  int lane = threadIdx.x & 63, wv = threadIdx.x >> 6;
  int bfb = blockIdx.x;
  int g = blockIdx.y * 4 + wv;
  int bf = bfb * 64 + lane;
  const float* src = partial + (size_t)g * BF2 + bfb * 64 + lane;
  float s = 0.f;
#pragma unroll
  for (int nt = 0; nt < NTIL; ++nt) s += src[(size_t)nt * 256 * BF2];
  if (bf < NBF) {
    int w = g >> 6, rem = g & 63, p = rem >> 2, comp = rem & 3;
    int i = (w >> 1) * 4 + (p >> 2);
    int j = (w & 1) * 4 + (p & 3);
    float* dst = (comp < 2) ? psd_s : psd_n;
    dst[(size_t)bf * 128 + (i * 8 + j) * 2 + (comp & 1)] = s;
  }
}

// K2: block per (b,c): feat -> MLP -> tanh -> gvec -> block reduce -> e[b*8+c].
__global__ __launch_bounds__(320) void k2_attn(
    const float* __restrict__ psd_s, const float* __restrict__ mlp_w,
    const float* __restrict__ mlp_b, const float* __restrict__ gvec_w,
    float* __restrict__ e_out) {
  __shared__ float feat[FFR];
  __shared__ float wred[5];
  int bx = blockIdx.x;
  int b = bx >> 3, c = bx & 7;
  int tid = threadIdx.x;
  int lane = tid & 63, wv = tid >> 6;
  if (tid < FFR) {
    const float* p = psd_s + (((size_t)(b * FFR + tid)) * 8 + c) * 16;
    float sre = 0.f, sim = 0.f;
#pragma unroll
    for (int e = 0; e < 8; ++e) {
      if (e != c) { sre += p[e * 2]; sim += p[e * 2 + 1]; }
    }
    sre *= (1.0f / 7.0f);
    sim *= (1.0f / 7.0f);
    feat[tid] = sqrtf(sre * sre + sim * sim);
  }
  __syncthreads();
  float acc = mlp_b[tid];
#pragma unroll 8
  for (int f = 0; f < FFR; ++f) acc += feat[f] * mlp_w[f * AAH + tid];
  float v = tanhf(acc) * gvec_w[tid];
#pragma unroll
  for (int off = 32; off > 0; off >>= 1) v += __shfl_down(v, off);
  if (lane == 0) wred[wv] = v;
  __syncthreads();
  if (tid == 0) e_out[bx] = wred[0] + wred[1] + wred[2] + wred[3] + wred[4];
}

// K3: one wave per (b,f); barrier-free Gauss-Jordan via shuffles; fused softmax.
__global__ __launch_bounds__(256) void k3_mvdr(
    const float* __restrict__ psd_s, const float* __restrict__ psd_n,
    const float* __restrict__ e_in, const float* __restrict__ gvec_b,
    float* __restrict__ ws) {
  int lane = threadIdx.x & 63, wv = threadIdx.x >> 6;
  int bf = blockIdx.x * 4 + wv;  // 514*4 == 2056 exact
  int b = bf / FFR;
  int r = lane >> 3, c = lane & 7;
  float2 n = ((const float2*)(psd_n + (size_t)bf * 128))[lane];
  float2 s = ((const float2*)(psd_s + (size_t)bf * 128))[lane];

#pragma unroll
  for (int k = 0; k < 8; ++k) {
    float pvre = __shfl(n.x, k * 9), pvim = __shfl(n.y, k * 9);
    float dinv = 1.f / (pvre * pvre + pvim * pvim);
    float pire = pvre * dinv, piim = -pvim * dinv;
    if (r == k) {
      float2 nn = n, ss = s;
      n.x = nn.x * pire - nn.y * piim; n.y = nn.x * piim + nn.y * pire;
      s.x = ss.x * pire - ss.y * piim; s.y = ss.x * piim + ss.y * pire;
    }
    float fre = __shfl(n.x, r * 8 + k), fim = __shfl(n.y, r * 8 + k);
    float pnre = __shfl(n.x, k * 8 + c), pnim = __shfl(n.y, k * 8 + c);
    float psre = __shfl(s.x, k * 8 + c), psim = __shfl(s.y, k * 8 + c);
    if (r != k) {
      n.x -= fre * pnre - fim * pnim; n.y -= fre * pnim + fim * pnre;
      s.x -= fre * psre - fim * psim; s.y -= fre * psim + fim * psre;
    }
  }
  float trx = (r == c) ? s.x : 0.f, tryy = (r == c) ? s.y : 0.f;
#pragma unroll
  for (int off = 1; off < 64; off <<= 1) {
    trx += __shfl_xor(trx, off);
    tryy += __shfl_xor(tryy, off);
  }
  float val = 2.f * (e_in[b * 8 + c] + gvec_b[0]);
  float mx = val;
#pragma unroll
  for (int off = 1; off < 8; off <<= 1) mx = fmaxf(mx, __shfl_xor(mx, off));
  float pe = expf(val - mx);
  float psum = pe;
#pragma unroll
  for (int off = 1; off < 8; off <<= 1) psum += __shfl_xor(psum, off);
  float uc = pe / psum;
  float wre = s.x * uc, wim = s.y * uc;
#pragma unroll
  for (int off = 1; off < 8; off <<= 1) {
    wre += __shfl_xor(wre, off);
    wim += __shfl_xor(wim, off);
  }
  float tre = trx + EPSF, tim = tryy;
  float d2 = 1.f / (tre * tre + tim * tim);
  float owre = (wre * tre + wim * tim) * d2;
  float owim = (wim * tre - wre * tim) * d2;
  if (c == 0) ((float2*)ws)[(size_t)bf * 8 + r] = make_float2(owre, owim);
}

// K4: block = (b, 4-t tile); stage ws[b] in padded LDS; coalesced f reads.
__global__ __launch_bounds__(256) void k4_beam(
    const float* __restrict__ dr, const float* __restrict__ di,
    const float* __restrict__ ws, float* __restrict__ out) {
  __shared__ float2 wsp[FFR * 9];
  int b = blockIdx.y;
  int t0 = blockIdx.x * 4;
  int tid = threadIdx.x;
  const float2* wsg = (const float2*)ws + (size_t)b * WSB;
  for (int i = tid; i < FFR * 8; i += 256) {
    int f = i >> 3, c = i & 7;
    wsp[f * 9 + c] = wsg[i];
  }
  __syncthreads();
  for (int ts = 0; ts < 4; ++ts) {
    int t = t0 + ts;
    const float* drb = dr + (size_t)(b * TTOT + t) * (CCH * FFR);
    const float* dib = di + (size_t)(b * TTOT + t) * (CCH * FFR);
    for (int f = tid; f < FFR; f += 256) {
      float are = 0.f, aim = 0.f;
#pragma unroll
      for (int c = 0; c < 8; ++c) {
        float xre = drb[c * FFR + f];
        float xim = dib[c * FFR + f];
        float2 w = wsp[f * 9 + c];
        are += w.x * xre + w.y * xim;
        aim += w.x * xim - w.y * xre;
      }
      ((float2*)out)[(size_t)(b * TTOT + t) * FFR + f] = make_float2(are, aim);
    }
  }
}

extern "C" void kernel_launch(void* const* d_in, const int* in_sizes, int n_in,
                              void* d_out, int out_size, void* d_ws, size_t ws_size,
                              hipStream_t stream) {
  const float* dr = (const float*)d_in[0];
  const float* di = (const float*)d_in[1];
  const float* mask_s = (const float*)d_in[2];
  const float* mask_n = (const float*)d_in[3];
  const float* mlp_w = (const float*)d_in[4];
  const float* mlp_b = (const float*)d_in[5];
  const float* gvec_w = (const float*)d_in[6];
  const float* gvec_b = (const float*)d_in[7];
  float* out = (float*)d_out;

  float* wsf = (float*)d_ws;
  float* mbar_s = wsf + OFF_MBS;
  float* mbar_n = wsf + OFF_MBN;
  float* part = wsf + OFF_PART;
  float* psd_s = wsf + OFF_PSDS;
  float* psd_n = wsf + OFF_PSDN;
  float* e_arr = wsf + OFF_E;
  float* wsv = wsf + OFF_WS;

  hipLaunchKernelGGL(k_mask, dim3(NBF), dim3(128), 0, stream,
                     mask_s, mask_n, mbar_s, mbar_n);
  hipLaunchKernelGGL(k_psd, dim3(33, NTIL), dim3(256), 0, stream,
                     dr, di, mbar_s, mbar_n, part);
  hipLaunchKernelGGL(k_reduce, dim3(33, 64), dim3(256), 0, stream,
                     part, psd_s, psd_n);
  hipLaunchKernelGGL(k2_attn, dim3(64), dim3(320), 0, stream,
                     psd_s, mlp_w, mlp_b, gvec_w, e_arr);
  hipLaunchKernelGGL(k3_mvdr, dim3(514), dim3(256), 0, stream,
                     psd_s, psd_n, e_arr, gvec_b, wsv);
  hipLaunchKernelGGL(k4_beam, dim3(128, 8), dim3(256), 0, stream, dr, di, wsv, out);
}